// Round 1
// baseline (1092.561 us; speedup 1.0000x reference)
//
#include <hip/hip_runtime.h>
#include <hip/hip_bf16.h>
#include <math.h>

using v8s   = __attribute__((ext_vector_type(8))) short;
using f32x4 = __attribute__((ext_vector_type(4))) float;

#define DEV __device__ __forceinline__

DEV void gload16(const void* g, void* l) {
  __builtin_amdgcn_global_load_lds(
      (const __attribute__((address_space(1))) unsigned int*)g,
      (__attribute__((address_space(3))) unsigned int*)l,
      16, 0, 0);
}

// ---------------------------------------------------------------- transpose+cast
// out[n][k] = bf16(in[k][n]);  in is [K][N] fp32 row-major.
__global__ __launch_bounds__(256) void transpose_cast(
    const float* __restrict__ in, __hip_bfloat16* __restrict__ out, int K, int N)
{
  __shared__ float tile[32][33];
  const int n0 = blockIdx.x * 32, k0 = blockIdx.y * 32;
  const int tx = threadIdx.x, ty = threadIdx.y;   // 32 x 8
#pragma unroll
  for (int j = 0; j < 4; ++j)
    tile[ty + j*8][tx] = in[(size_t)(k0 + ty + j*8) * N + n0 + tx];
  __syncthreads();
#pragma unroll
  for (int j = 0; j < 4; ++j)
    out[(size_t)(n0 + ty + j*8) * K + k0 + tx] = __float2bfloat16(tile[tx][ty + j*8]);
}

// ---------------------------------------------------------------- layernorm (fp32 in -> bf16 out)
__global__ __launch_bounds__(256) void ln_kernel(
    const float* __restrict__ xin, const float* __restrict__ g,
    const float* __restrict__ b, __hip_bfloat16* __restrict__ outp)
{
  const int row = blockIdx.x;
  const int t = threadIdx.x;
  const float4 v = ((const float4*)(xin + (size_t)row * 1024))[t];
  float s  = v.x + v.y + v.z + v.w;
  float ss = v.x*v.x + v.y*v.y + v.z*v.z + v.w*v.w;
  for (int off = 32; off > 0; off >>= 1) { s += __shfl_down(s, off); ss += __shfl_down(ss, off); }
  __shared__ float red[8];
  const int w = t >> 6;
  if ((t & 63) == 0) { red[w*2] = s; red[w*2 + 1] = ss; }
  __syncthreads();
  s  = red[0] + red[2] + red[4] + red[6];
  ss = red[1] + red[3] + red[5] + red[7];
  const float mu   = s * (1.0f / 1024.0f);
  const float rstd = rsqrtf(ss * (1.0f / 1024.0f) - mu * mu + 1e-5f);
  const float4 gv = ((const float4*)g)[t];
  const float4 bv = ((const float4*)b)[t];
  __hip_bfloat16* o = outp + (size_t)row * 1024 + t * 4;
  o[0] = __float2bfloat16((v.x - mu) * rstd * gv.x + bv.x);
  o[1] = __float2bfloat16((v.y - mu) * rstd * gv.y + bv.y);
  o[2] = __float2bfloat16((v.z - mu) * rstd * gv.z + bv.z);
  o[3] = __float2bfloat16((v.w - mu) * rstd * gv.w + bv.w);
}

// ---------------------------------------------------------------- GEMM  C = A[M,K] * Bt[N,K]^T + bias, epilogues
// EPI 0: bf16 store   1: fp32 store + residual   2: gelu -> bf16   3: qkv scatter (v transposed)
template<int EPI>
__global__ __launch_bounds__(256) void gemm_bt(
    const __hip_bfloat16* __restrict__ A, const __hip_bfloat16* __restrict__ Bt,
    const float* __restrict__ bias, const float* resid, void* outp,
    __hip_bfloat16* __restrict__ vt, int M, int N, int K)
{
  __shared__ __hip_bfloat16 As[128 * 64];
  __shared__ __hip_bfloat16 Bs[128 * 64];
  const int t = threadIdx.x;
  const int w = t >> 6, l = t & 63;
  const int wm = w >> 1, wn = w & 1;
  const int lr = l & 15, lg = l >> 4;
  const int bx = blockIdx.x, by = blockIdx.y;

  const f32x4 zz = {0.f, 0.f, 0.f, 0.f};
  f32x4 acc[4][4];
#pragma unroll
  for (int i = 0; i < 4; ++i)
#pragma unroll
    for (int j = 0; j < 4; ++j) acc[i][j] = zz;

  const int nkt = K >> 6;
  for (int kt = 0; kt < nkt; ++kt) {
    __syncthreads();
#pragma unroll
    for (int rr = 0; rr < 4; ++rr) {
      const int c = rr * 256 + t;
      const int row = c >> 3, kc = c & 7;
      gload16(A  + (size_t)(by * 128 + row) * K + kt * 64 + kc * 8, (__hip_bfloat16*)As + c * 8);
      gload16(Bt + (size_t)(bx * 128 + row) * K + kt * 64 + kc * 8, (__hip_bfloat16*)Bs + c * 8);
    }
    __syncthreads();
#pragma unroll
    for (int k2 = 0; k2 < 2; ++k2) {
      v8s av[4], bv[4];
#pragma unroll
      for (int i = 0; i < 4; ++i)
        av[i] = *(const v8s*)(As + (wm * 64 + i * 16 + lr) * 64 + k2 * 32 + lg * 8);
#pragma unroll
      for (int j = 0; j < 4; ++j)
        bv[j] = *(const v8s*)(Bs + (wn * 64 + j * 16 + lr) * 64 + k2 * 32 + lg * 8);
#pragma unroll
      for (int i = 0; i < 4; ++i)
#pragma unroll
        for (int j = 0; j < 4; ++j)
          acc[i][j] = __builtin_amdgcn_mfma_f32_16x16x32_bf16(av[i], bv[j], acc[i][j], 0, 0, 0);
    }
  }

#pragma unroll
  for (int i = 0; i < 4; ++i)
#pragma unroll
    for (int j = 0; j < 4; ++j) {
      const int col = bx * 128 + wn * 64 + j * 16 + lr;
      const float bz = bias[col];
#pragma unroll
      for (int r = 0; r < 4; ++r) {
        const int row = by * 128 + wm * 64 + i * 16 + lg * 4 + r;
        const float v = acc[i][j][r] + bz;
        if (EPI == 0) {
          ((__hip_bfloat16*)outp)[(size_t)row * N + col] = __float2bfloat16(v);
        } else if (EPI == 1) {
          ((float*)outp)[(size_t)row * N + col] = v + resid[(size_t)row * N + col];
        } else if (EPI == 2) {
          const float gel = 0.5f * v * (1.0f + erff(v * 0.70710678118654752f));
          ((__hip_bfloat16*)outp)[(size_t)row * N + col] = __float2bfloat16(gel);
        } else {
          if (col < 2048) {
            ((__hip_bfloat16*)outp)[(size_t)row * 3072 + col] = __float2bfloat16(v);
          } else {
            const int d = col - 2048;
            const int hh = d >> 6, dd = d & 63;
            const int bbq = row >> 10, nn = row & 1023;
            vt[(((size_t)bbq * 16 + hh) * 64 + dd) * 1024 + nn] = __float2bfloat16(v);
          }
        }
      }
    }
}

// ---------------------------------------------------------------- flash attention
// grid (8 q-tiles, 256 heads), 256 threads. Q-tile 128 rows (wave owns 32), KV-tile 64.
__global__ __launch_bounds__(256) void attn_kernel(
    const __hip_bfloat16* __restrict__ qkv, const __hip_bfloat16* __restrict__ vt,
    __hip_bfloat16* __restrict__ ctx)
{
  __shared__ __hip_bfloat16 Ks[64 * 64];    // [kv_n][d]
  __shared__ __hip_bfloat16 Vs[64 * 64];    // [d][kv_n]  (from vt)
  __shared__ __hip_bfloat16 Ps[4 * 32 * 64];// per-wave P [32 q][64 kv]

  const int t = threadIdx.x;
  const int w = t >> 6, l = t & 63;
  const int lr = l & 15, lg = l >> 4;
  const int head = blockIdx.y;             // 0..255
  const int bb = head >> 4, h = head & 15;
  const int q0 = blockIdx.x * 128;
  const int tok0 = bb * 1024;
  const int qrow_base = tok0 + q0 + w * 32;

  // Q fragments (2 row-subtiles x 2 k-chunks), direct from global
  v8s qf[2][2];
#pragma unroll
  for (int i = 0; i < 2; ++i)
#pragma unroll
    for (int k2 = 0; k2 < 2; ++k2)
      qf[i][k2] = *(const v8s*)(qkv + (size_t)(qrow_base + i * 16 + lr) * 3072 + h * 64 + k2 * 32 + lg * 8);

  const f32x4 zz = {0.f, 0.f, 0.f, 0.f};
  f32x4 oacc[2][4];
#pragma unroll
  for (int i = 0; i < 2; ++i)
#pragma unroll
    for (int dg = 0; dg < 4; ++dg) oacc[i][dg] = zz;
  float mstat[2][4], lstat[2][4];
#pragma unroll
  for (int i = 0; i < 2; ++i)
#pragma unroll
    for (int r = 0; r < 4; ++r) { mstat[i][r] = -1e30f; lstat[i][r] = 0.f; }

  for (int kt = 0; kt < 16; ++kt) {
    __syncthreads();
#pragma unroll
    for (int rr = 0; rr < 2; ++rr) {
      const int c = rr * 256 + t;
      const int n = c >> 3, kc = c & 7;
      gload16(qkv + (size_t)(tok0 + kt * 64 + n) * 3072 + 1024 + h * 64 + kc * 8,
              (__hip_bfloat16*)Ks + c * 8);
      gload16(vt + (size_t)(head * 64 + n) * 1024 + kt * 64 + kc * 8,
              (__hip_bfloat16*)Vs + c * 8);
    }
    __syncthreads();

    // S = Q K^T
    f32x4 s[2][4];
#pragma unroll
    for (int i = 0; i < 2; ++i)
#pragma unroll
      for (int j = 0; j < 4; ++j) s[i][j] = zz;
#pragma unroll
    for (int k2 = 0; k2 < 2; ++k2) {
      v8s kb[4];
#pragma unroll
      for (int j = 0; j < 4; ++j)
        kb[j] = *(const v8s*)(Ks + (j * 16 + lr) * 64 + k2 * 32 + lg * 8);
#pragma unroll
      for (int i = 0; i < 2; ++i)
#pragma unroll
        for (int j = 0; j < 4; ++j)
          s[i][j] = __builtin_amdgcn_mfma_f32_16x16x32_bf16(qf[i][k2], kb[j], s[i][j], 0, 0, 0);
    }

    // online softmax (rows live in lanes sharing lg; cols across lr)
#pragma unroll
    for (int i = 0; i < 2; ++i) {
#pragma unroll
      for (int j = 0; j < 4; ++j)
#pragma unroll
        for (int r = 0; r < 4; ++r) s[i][j][r] *= 0.125f;
      float tm[4], mnew[4], al[4], rsum[4];
#pragma unroll
      for (int r = 0; r < 4; ++r)
        tm[r] = fmaxf(fmaxf(s[i][0][r], s[i][1][r]), fmaxf(s[i][2][r], s[i][3][r]));
#pragma unroll
      for (int off = 1; off < 16; off <<= 1)
#pragma unroll
        for (int r = 0; r < 4; ++r) tm[r] = fmaxf(tm[r], __shfl_xor(tm[r], off));
#pragma unroll
      for (int r = 0; r < 4; ++r) {
        mnew[r] = fmaxf(mstat[i][r], tm[r]);
        al[r] = __expf(mstat[i][r] - mnew[r]);
        mstat[i][r] = mnew[r];
        rsum[r] = 0.f;
      }
#pragma unroll
      for (int j = 0; j < 4; ++j)
#pragma unroll
        for (int r = 0; r < 4; ++r) {
          const float p = __expf(s[i][j][r] - mnew[r]);
          s[i][j][r] = p;
          rsum[r] += p;
        }
#pragma unroll
      for (int off = 1; off < 16; off <<= 1)
#pragma unroll
        for (int r = 0; r < 4; ++r) rsum[r] += __shfl_xor(rsum[r], off);
#pragma unroll
      for (int r = 0; r < 4; ++r) lstat[i][r] = lstat[i][r] * al[r] + rsum[r];
#pragma unroll
      for (int dg = 0; dg < 4; ++dg)
#pragma unroll
        for (int r = 0; r < 4; ++r) oacc[i][dg][r] *= al[r];
      // P -> LDS (bf16), D-layout scatter
#pragma unroll
      for (int j = 0; j < 4; ++j)
#pragma unroll
        for (int r = 0; r < 4; ++r)
          Ps[w * 2048 + (i * 16 + lg * 4 + r) * 64 + j * 16 + lr] = __float2bfloat16(s[i][j][r]);
    }

    // O += P V
#pragma unroll
    for (int k2 = 0; k2 < 2; ++k2) {
      v8s pa[2];
#pragma unroll
      for (int i = 0; i < 2; ++i)
        pa[i] = *(const v8s*)(Ps + w * 2048 + (i * 16 + lr) * 64 + k2 * 32 + lg * 8);
#pragma unroll
      for (int dg = 0; dg < 4; ++dg) {
        v8s vb = *(const v8s*)(Vs + (dg * 16 + lr) * 64 + k2 * 32 + lg * 8);
#pragma unroll
        for (int i = 0; i < 2; ++i)
          oacc[i][dg] = __builtin_amdgcn_mfma_f32_16x16x32_bf16(pa[i], vb, oacc[i][dg], 0, 0, 0);
      }
    }
  }

#pragma unroll
  for (int i = 0; i < 2; ++i)
#pragma unroll
    for (int dg = 0; dg < 4; ++dg)
#pragma unroll
      for (int r = 0; r < 4; ++r) {
        const int qrow = qrow_base + i * 16 + lg * 4 + r;
        const float ov = oacc[i][dg][r] / lstat[i][r];
        ctx[(size_t)qrow * 1024 + h * 64 + dg * 16 + lr] = __float2bfloat16(ov);
      }
}

// ---------------------------------------------------------------- launch
extern "C" void kernel_launch(void* const* d_in, const int* in_sizes, int n_in,
                              void* d_out, int out_size, void* d_ws, size_t ws_size,
                              hipStream_t stream) {
  const float* x      = (const float*)d_in[0];
  const float* ln1_g  = (const float*)d_in[1];
  const float* ln1_b  = (const float*)d_in[2];
  const float* w_qkv  = (const float*)d_in[3];
  const float* b_qkv  = (const float*)d_in[4];
  const float* w_proj = (const float*)d_in[5];
  const float* b_proj = (const float*)d_in[6];
  const float* ln2_g  = (const float*)d_in[7];
  const float* ln2_b  = (const float*)d_in[8];
  const float* w_fc1  = (const float*)d_in[9];
  const float* b_fc1  = (const float*)d_in[10];
  const float* w_fc2  = (const float*)d_in[11];
  const float* b_fc2  = (const float*)d_in[12];
  float* out = (float*)d_out;

  char* ws = (char*)d_ws;
  size_t off = 0;
  auto alloc = [&](size_t bytes) { char* p = ws + off; off += bytes; return p; };
  __hip_bfloat16* wqkvt  = (__hip_bfloat16*)alloc((size_t)3072 * 1024 * 2);
  __hip_bfloat16* wprojt = (__hip_bfloat16*)alloc((size_t)1024 * 1024 * 2);
  __hip_bfloat16* wfc1t  = (__hip_bfloat16*)alloc((size_t)4096 * 1024 * 2);
  __hip_bfloat16* wfc2t  = (__hip_bfloat16*)alloc((size_t)1024 * 4096 * 2);
  __hip_bfloat16* h      = (__hip_bfloat16*)alloc((size_t)16384 * 1024 * 2);
  __hip_bfloat16* qkvb   = (__hip_bfloat16*)alloc((size_t)16384 * 3072 * 2);
  __hip_bfloat16* vt     = (__hip_bfloat16*)alloc((size_t)256 * 64 * 1024 * 2);
  __hip_bfloat16* ctx    = (__hip_bfloat16*)alloc((size_t)16384 * 1024 * 2);
  __hip_bfloat16* mbuf   = qkvb;  // [16384,4096] bf16 reuses qkv+vt (exactly 134,217,728 B)

  transpose_cast<<<dim3(3072/32, 1024/32), dim3(32, 8), 0, stream>>>(w_qkv,  wqkvt,  1024, 3072);
  transpose_cast<<<dim3(1024/32, 1024/32), dim3(32, 8), 0, stream>>>(w_proj, wprojt, 1024, 1024);
  transpose_cast<<<dim3(4096/32, 1024/32), dim3(32, 8), 0, stream>>>(w_fc1,  wfc1t,  1024, 4096);
  transpose_cast<<<dim3(1024/32, 4096/32), dim3(32, 8), 0, stream>>>(w_fc2,  wfc2t,  4096, 1024);

  ln_kernel<<<16384, 256, 0, stream>>>(x, ln1_g, ln1_b, h);
  gemm_bt<3><<<dim3(3072/128, 16384/128), 256, 0, stream>>>(h, wqkvt, b_qkv, nullptr, qkvb, vt, 16384, 3072, 1024);
  attn_kernel<<<dim3(8, 256), 256, 0, stream>>>(qkvb, vt, ctx);
  gemm_bt<1><<<dim3(1024/128, 16384/128), 256, 0, stream>>>(ctx, wprojt, b_proj, x, d_out, nullptr, 16384, 1024, 1024);
  ln_kernel<<<16384, 256, 0, stream>>>(out, ln2_g, ln2_b, h);
  gemm_bt<2><<<dim3(4096/128, 16384/128), 256, 0, stream>>>(h, wfc1t, b_fc1, nullptr, mbuf, nullptr, 16384, 4096, 1024);
  gemm_bt<1><<<dim3(1024/128, 16384/128), 256, 0, stream>>>(mbuf, wfc2t, b_fc2, out, d_out, nullptr, 16384, 1024, 4096);
}

// Round 2
// 953.694 us; speedup vs baseline: 1.1456x; 1.1456x over previous
//
#include <hip/hip_runtime.h>
#include <hip/hip_bf16.h>
#include <math.h>

using v8s   = __attribute__((ext_vector_type(8))) short;
using f32x4 = __attribute__((ext_vector_type(4))) float;

#define DEV __device__ __forceinline__

DEV void gload16(const void* g, void* l) {
  __builtin_amdgcn_global_load_lds(
      (const __attribute__((address_space(1))) unsigned int*)g,
      (__attribute__((address_space(3))) unsigned int*)l,
      16, 0, 0);
}

// ---------------------------------------------------------------- transpose+cast
__global__ __launch_bounds__(256) void transpose_cast(
    const float* __restrict__ in, __hip_bfloat16* __restrict__ out, int K, int N)
{
  __shared__ float tile[32][33];
  const int n0 = blockIdx.x * 32, k0 = blockIdx.y * 32;
  const int tx = threadIdx.x, ty = threadIdx.y;   // 32 x 8
#pragma unroll
  for (int j = 0; j < 4; ++j)
    tile[ty + j*8][tx] = in[(size_t)(k0 + ty + j*8) * N + n0 + tx];
  __syncthreads();
#pragma unroll
  for (int j = 0; j < 4; ++j)
    out[(size_t)(n0 + ty + j*8) * K + k0 + tx] = __float2bfloat16(tile[tx][ty + j*8]);
}

// ---------------------------------------------------------------- layernorm
__global__ __launch_bounds__(256) void ln_kernel(
    const float* __restrict__ xin, const float* __restrict__ g,
    const float* __restrict__ b, __hip_bfloat16* __restrict__ outp)
{
  const int row = blockIdx.x;
  const int t = threadIdx.x;
  const float4 v = ((const float4*)(xin + (size_t)row * 1024))[t];
  float s  = v.x + v.y + v.z + v.w;
  float ss = v.x*v.x + v.y*v.y + v.z*v.z + v.w*v.w;
  for (int off = 32; off > 0; off >>= 1) { s += __shfl_down(s, off); ss += __shfl_down(ss, off); }
  __shared__ float red[8];
  const int w = t >> 6;
  if ((t & 63) == 0) { red[w*2] = s; red[w*2 + 1] = ss; }
  __syncthreads();
  s  = red[0] + red[2] + red[4] + red[6];
  ss = red[1] + red[3] + red[5] + red[7];
  const float mu   = s * (1.0f / 1024.0f);
  const float rstd = rsqrtf(ss * (1.0f / 1024.0f) - mu * mu + 1e-5f);
  const float4 gv = ((const float4*)g)[t];
  const float4 bv = ((const float4*)b)[t];
  __hip_bfloat16* o = outp + (size_t)row * 1024 + t * 4;
  o[0] = __float2bfloat16((v.x - mu) * rstd * gv.x + bv.x);
  o[1] = __float2bfloat16((v.y - mu) * rstd * gv.y + bv.y);
  o[2] = __float2bfloat16((v.z - mu) * rstd * gv.z + bv.z);
  o[3] = __float2bfloat16((v.w - mu) * rstd * gv.w + bv.w);
}

// ---------------------------------------------------------------- 256x256 8-phase GEMM
// C = A[M,K] * Bt[N,K]^T + bias.  EPI 1: fp32 + resid  2: gelu->bf16  3: qkv scatter
// 512 threads = 8 waves (2M x 4N); per-wave 128x64; BK=64 split into two k-halves.
// LDS swizzle: slot' = slot ^ ((row>>1)&3)  (4 x 16B slots per 64B row).

#define STAGE_A(tile, ks, buf) do { int tt_ = (tile) < NT ? (tile) : NT - 1;     \
  _Pragma("unroll") for (int rr_ = 0; rr_ < 2; ++rr_) {                          \
    const int c_ = rr_*512 + t; const int row_ = c_ >> 2; const int sl_ = c_ & 3;\
    const int sw_ = sl_ ^ ((row_ >> 1) & 3);                                     \
    gload16(A + (size_t)(bm0 + row_) * K + tt_*64 + (ks)*32 + sw_*8,             \
            &As[buf][ks][row_][sl_*8]); } } while (0)

#define STAGE_B(tile, ks, buf) do { int tt_ = (tile) < NT ? (tile) : NT - 1;     \
  _Pragma("unroll") for (int rr_ = 0; rr_ < 2; ++rr_) {                          \
    const int c_ = rr_*512 + t; const int row_ = c_ >> 2; const int sl_ = c_ & 3;\
    const int sw_ = sl_ ^ ((row_ >> 1) & 3);                                     \
    gload16(Bt + (size_t)(bn0 + row_) * K + tt_*64 + (ks)*32 + sw_*8,            \
            &Bs[buf][ks][row_][sl_*8]); } } while (0)

#define PHASE(BUF, KS, MH, STAGE_STMT, VM8) do {                                 \
  v8s a_[4], b_[4];                                                              \
  _Pragma("unroll") for (int mi_ = 0; mi_ < 4; ++mi_) {                          \
    const int row_ = awrow + ((MH)*4 + mi_) * 16;                                \
    a_[mi_] = *(const v8s*)&As[BUF][KS][row_][(lg ^ ((row_>>1)&3))*8]; }         \
  _Pragma("unroll") for (int n_ = 0; n_ < 4; ++n_) {                             \
    const int row_ = bwrow + n_*16;                                              \
    b_[n_] = *(const v8s*)&Bs[BUF][KS][row_][(lg ^ ((row_>>1)&3))*8]; }          \
  STAGE_STMT;                                                                    \
  __builtin_amdgcn_s_barrier();                                                  \
  asm volatile("s_waitcnt lgkmcnt(0)" ::: "memory");                             \
  __builtin_amdgcn_sched_barrier(0);                                             \
  __builtin_amdgcn_s_setprio(1);                                                 \
  _Pragma("unroll") for (int mi_ = 0; mi_ < 4; ++mi_)                            \
    _Pragma("unroll") for (int n_ = 0; n_ < 4; ++n_)                             \
      acc[(MH)*4 + mi_][n_] = __builtin_amdgcn_mfma_f32_16x16x32_bf16(           \
          a_[mi_], b_[n_], acc[(MH)*4 + mi_][n_], 0, 0, 0);                      \
  __builtin_amdgcn_s_setprio(0);                                                 \
  if (VM8) asm volatile("s_waitcnt vmcnt(8)" ::: "memory");                      \
  __builtin_amdgcn_s_barrier();                                                  \
} while (0)

template<int EPI>
__global__ __launch_bounds__(512, 2) void gemm256(
    const __hip_bfloat16* __restrict__ A, const __hip_bfloat16* __restrict__ Bt,
    const float* __restrict__ bias, const float* resid, void* outp,
    __hip_bfloat16* __restrict__ vt, int N, int K, int nbx)
{
  __shared__ __hip_bfloat16 As[2][2][256][32];   // [buf][khalf][row][slot*8+e]
  __shared__ __hip_bfloat16 Bs[2][2][256][32];

  const int t = threadIdx.x;
  const int w = t >> 6, l = t & 63;
  const int wm = w >> 2, wn = w & 3;
  const int lr = l & 15, lg = l >> 4;
  const int awrow = wm * 128 + lr;
  const int bwrow = wn * 64 + lr;

  // T1: bijective XCD swizzle (gridDim.x % 8 == 0 for all our shapes)
  int wg = blockIdx.x;
  const int cpx = gridDim.x >> 3;
  wg = (wg & 7) * cpx + (wg >> 3);
  const int by = wg / nbx, bx = wg % nbx;
  const size_t bm0 = (size_t)by * 256, bn0 = (size_t)bx * 256;

  const int NT = K >> 6;   // 16 or 64, always even

  const f32x4 zz = {0.f, 0.f, 0.f, 0.f};
  f32x4 acc[8][4];
#pragma unroll
  for (int i = 0; i < 8; ++i)
#pragma unroll
    for (int j = 0; j < 4; ++j) acc[i][j] = zz;

  // ---- prologue: tile0 (all), tile1 k0; full drain once
  STAGE_A(0, 0, 0); STAGE_B(0, 0, 0);
  STAGE_A(0, 1, 0); STAGE_B(0, 1, 0);
  STAGE_A(1, 0, 1); STAGE_B(1, 0, 1);
  asm volatile("s_waitcnt vmcnt(0)" ::: "memory");
  __builtin_amdgcn_s_barrier();

  // ---- main loop: iter i handles tiles 2i (buf0) and 2i+1 (buf1), 8 phases
  const int NI = NT >> 1;
  for (int i = 0; i < NI; ++i) {
    const int tE = 2 * i;
    PHASE(0, 0, 0, STAGE_A(tE + 1, 1, 1), 0);   // p1: stage A-k1(2i+1)
    PHASE(0, 0, 1, STAGE_B(tE + 1, 1, 1), 1);   // p2: stage B-k1(2i+1)
    PHASE(0, 1, 0, STAGE_A(tE + 2, 0, 0), 0);   // p3: stage A-k0(2i+2)
    PHASE(0, 1, 1, STAGE_B(tE + 2, 0, 0), 1);   // p4
    PHASE(1, 0, 0, STAGE_A(tE + 2, 1, 0), 0);   // p5: stage A-k1(2i+2)
    PHASE(1, 0, 1, STAGE_B(tE + 2, 1, 0), 1);   // p6
    PHASE(1, 1, 0, STAGE_A(tE + 3, 0, 1), 0);   // p7: stage A-k0(2i+3)
    PHASE(1, 1, 1, STAGE_B(tE + 3, 0, 1), 1);   // p8
  }

  // ---- epilogue
#pragma unroll
  for (int m = 0; m < 8; ++m)
#pragma unroll
    for (int n = 0; n < 4; ++n) {
      const int col = (int)bn0 + wn * 64 + n * 16 + lr;
      const float bz = bias[col];
#pragma unroll
      for (int r = 0; r < 4; ++r) {
        const int row = (int)bm0 + wm * 128 + m * 16 + lg * 4 + r;
        const float v = acc[m][n][r] + bz;
        if (EPI == 1) {
          ((float*)outp)[(size_t)row * N + col] = v + resid[(size_t)row * N + col];
        } else if (EPI == 2) {
          const float gel = 0.5f * v * (1.0f + erff(v * 0.70710678118654752f));
          ((__hip_bfloat16*)outp)[(size_t)row * N + col] = __float2bfloat16(gel);
        } else {
          if (col < 2048) {
            ((__hip_bfloat16*)outp)[(size_t)row * 3072 + col] = __float2bfloat16(v);
          } else {
            const int d = col - 2048;
            const int hh = d >> 6, dd = d & 63;
            const int bbq = row >> 10, nn = row & 1023;
            vt[(((size_t)bbq * 16 + hh) * 64 + dd) * 1024 + nn] = __float2bfloat16(v);
          }
        }
      }
    }
}

// ---------------------------------------------------------------- flash attention (unchanged)
__global__ __launch_bounds__(256) void attn_kernel(
    const __hip_bfloat16* __restrict__ qkv, const __hip_bfloat16* __restrict__ vt,
    __hip_bfloat16* __restrict__ ctx)
{
  __shared__ __hip_bfloat16 Ks[64 * 64];
  __shared__ __hip_bfloat16 Vs[64 * 64];
  __shared__ __hip_bfloat16 Ps[4 * 32 * 64];

  const int t = threadIdx.x;
  const int w = t >> 6, l = t & 63;
  const int lr = l & 15, lg = l >> 4;
  const int head = blockIdx.y;
  const int bb = head >> 4, h = head & 15;
  const int q0 = blockIdx.x * 128;
  const int tok0 = bb * 1024;
  const int qrow_base = tok0 + q0 + w * 32;

  v8s qf[2][2];
#pragma unroll
  for (int i = 0; i < 2; ++i)
#pragma unroll
    for (int k2 = 0; k2 < 2; ++k2)
      qf[i][k2] = *(const v8s*)(qkv + (size_t)(qrow_base + i * 16 + lr) * 3072 + h * 64 + k2 * 32 + lg * 8);

  const f32x4 zz = {0.f, 0.f, 0.f, 0.f};
  f32x4 oacc[2][4];
#pragma unroll
  for (int i = 0; i < 2; ++i)
#pragma unroll
    for (int dg = 0; dg < 4; ++dg) oacc[i][dg] = zz;
  float mstat[2][4], lstat[2][4];
#pragma unroll
  for (int i = 0; i < 2; ++i)
#pragma unroll
    for (int r = 0; r < 4; ++r) { mstat[i][r] = -1e30f; lstat[i][r] = 0.f; }

  for (int kt = 0; kt < 16; ++kt) {
    __syncthreads();
#pragma unroll
    for (int rr = 0; rr < 2; ++rr) {
      const int c = rr * 256 + t;
      const int n = c >> 3, kc = c & 7;
      gload16(qkv + (size_t)(tok0 + kt * 64 + n) * 3072 + 1024 + h * 64 + kc * 8,
              (__hip_bfloat16*)Ks + c * 8);
      gload16(vt + (size_t)(head * 64 + n) * 1024 + kt * 64 + kc * 8,
              (__hip_bfloat16*)Vs + c * 8);
    }
    __syncthreads();

    f32x4 s[2][4];
#pragma unroll
    for (int i = 0; i < 2; ++i)
#pragma unroll
      for (int j = 0; j < 4; ++j) s[i][j] = zz;
#pragma unroll
    for (int k2 = 0; k2 < 2; ++k2) {
      v8s kb[4];
#pragma unroll
      for (int j = 0; j < 4; ++j)
        kb[j] = *(const v8s*)(Ks + (j * 16 + lr) * 64 + k2 * 32 + lg * 8);
#pragma unroll
      for (int i = 0; i < 2; ++i)
#pragma unroll
        for (int j = 0; j < 4; ++j)
          s[i][j] = __builtin_amdgcn_mfma_f32_16x16x32_bf16(qf[i][k2], kb[j], s[i][j], 0, 0, 0);
    }

#pragma unroll
    for (int i = 0; i < 2; ++i) {
#pragma unroll
      for (int j = 0; j < 4; ++j)
#pragma unroll
        for (int r = 0; r < 4; ++r) s[i][j][r] *= 0.125f;
      float tm[4], mnew[4], al[4], rsum[4];
#pragma unroll
      for (int r = 0; r < 4; ++r)
        tm[r] = fmaxf(fmaxf(s[i][0][r], s[i][1][r]), fmaxf(s[i][2][r], s[i][3][r]));
#pragma unroll
      for (int off = 1; off < 16; off <<= 1)
#pragma unroll
        for (int r = 0; r < 4; ++r) tm[r] = fmaxf(tm[r], __shfl_xor(tm[r], off));
#pragma unroll
      for (int r = 0; r < 4; ++r) {
        mnew[r] = fmaxf(mstat[i][r], tm[r]);
        al[r] = __expf(mstat[i][r] - mnew[r]);
        mstat[i][r] = mnew[r];
        rsum[r] = 0.f;
      }
#pragma unroll
      for (int j = 0; j < 4; ++j)
#pragma unroll
        for (int r = 0; r < 4; ++r) {
          const float p = __expf(s[i][j][r] - mnew[r]);
          s[i][j][r] = p;
          rsum[r] += p;
        }
#pragma unroll
      for (int off = 1; off < 16; off <<= 1)
#pragma unroll
        for (int r = 0; r < 4; ++r) rsum[r] += __shfl_xor(rsum[r], off);
#pragma unroll
      for (int r = 0; r < 4; ++r) lstat[i][r] = lstat[i][r] * al[r] + rsum[r];
#pragma unroll
      for (int dg = 0; dg < 4; ++dg)
#pragma unroll
        for (int r = 0; r < 4; ++r) oacc[i][dg][r] *= al[r];
#pragma unroll
      for (int j = 0; j < 4; ++j)
#pragma unroll
        for (int r = 0; r < 4; ++r)
          Ps[w * 2048 + (i * 16 + lg * 4 + r) * 64 + j * 16 + lr] = __float2bfloat16(s[i][j][r]);
    }

#pragma unroll
    for (int k2 = 0; k2 < 2; ++k2) {
      v8s pa[2];
#pragma unroll
      for (int i = 0; i < 2; ++i)
        pa[i] = *(const v8s*)(Ps + w * 2048 + (i * 16 + lr) * 64 + k2 * 32 + lg * 8);
#pragma unroll
      for (int dg = 0; dg < 4; ++dg) {
        v8s vb = *(const v8s*)(Vs + (dg * 16 + lr) * 64 + k2 * 32 + lg * 8);
#pragma unroll
        for (int i = 0; i < 2; ++i)
          oacc[i][dg] = __builtin_amdgcn_mfma_f32_16x16x32_bf16(pa[i], vb, oacc[i][dg], 0, 0, 0);
      }
    }
  }

#pragma unroll
  for (int i = 0; i < 2; ++i)
#pragma unroll
    for (int dg = 0; dg < 4; ++dg)
#pragma unroll
      for (int r = 0; r < 4; ++r) {
        const int qrow = qrow_base + i * 16 + lg * 4 + r;
        const float ov = oacc[i][dg][r] / lstat[i][r];
        ctx[(size_t)qrow * 1024 + h * 64 + dg * 16 + lr] = __float2bfloat16(ov);
      }
}

// ---------------------------------------------------------------- launch
extern "C" void kernel_launch(void* const* d_in, const int* in_sizes, int n_in,
                              void* d_out, int out_size, void* d_ws, size_t ws_size,
                              hipStream_t stream) {
  const float* x      = (const float*)d_in[0];
  const float* ln1_g  = (const float*)d_in[1];
  const float* ln1_b  = (const float*)d_in[2];
  const float* w_qkv  = (const float*)d_in[3];
  const float* b_qkv  = (const float*)d_in[4];
  const float* w_proj = (const float*)d_in[5];
  const float* b_proj = (const float*)d_in[6];
  const float* ln2_g  = (const float*)d_in[7];
  const float* ln2_b  = (const float*)d_in[8];
  const float* w_fc1  = (const float*)d_in[9];
  const float* b_fc1  = (const float*)d_in[10];
  const float* w_fc2  = (const float*)d_in[11];
  const float* b_fc2  = (const float*)d_in[12];
  float* out = (float*)d_out;

  char* ws = (char*)d_ws;
  size_t off = 0;
  auto alloc = [&](size_t bytes) { char* p = ws + off; off += bytes; return p; };
  __hip_bfloat16* wqkvt  = (__hip_bfloat16*)alloc((size_t)3072 * 1024 * 2);
  __hip_bfloat16* wprojt = (__hip_bfloat16*)alloc((size_t)1024 * 1024 * 2);
  __hip_bfloat16* wfc1t  = (__hip_bfloat16*)alloc((size_t)4096 * 1024 * 2);
  __hip_bfloat16* wfc2t  = (__hip_bfloat16*)alloc((size_t)1024 * 4096 * 2);
  __hip_bfloat16* h      = (__hip_bfloat16*)alloc((size_t)16384 * 1024 * 2);
  __hip_bfloat16* qkvb   = (__hip_bfloat16*)alloc((size_t)16384 * 3072 * 2);
  __hip_bfloat16* vt     = (__hip_bfloat16*)alloc((size_t)256 * 64 * 1024 * 2);
  __hip_bfloat16* ctx    = (__hip_bfloat16*)alloc((size_t)16384 * 1024 * 2);
  __hip_bfloat16* mbuf   = qkvb;  // [16384,4096] bf16 reuses qkv+vt

  transpose_cast<<<dim3(3072/32, 1024/32), dim3(32, 8), 0, stream>>>(w_qkv,  wqkvt,  1024, 3072);
  transpose_cast<<<dim3(1024/32, 1024/32), dim3(32, 8), 0, stream>>>(w_proj, wprojt, 1024, 1024);
  transpose_cast<<<dim3(4096/32, 1024/32), dim3(32, 8), 0, stream>>>(w_fc1,  wfc1t,  1024, 4096);
  transpose_cast<<<dim3(1024/32, 4096/32), dim3(32, 8), 0, stream>>>(w_fc2,  wfc2t,  4096, 1024);

  ln_kernel<<<16384, 256, 0, stream>>>(x, ln1_g, ln1_b, h);
  gemm256<3><<<12 * 64, 512, 0, stream>>>(h,    wqkvt,  b_qkv,  nullptr, qkvb,  vt,      3072, 1024, 12);
  attn_kernel<<<dim3(8, 256), 256, 0, stream>>>(qkvb, vt, ctx);
  gemm256<1><<< 4 * 64, 512, 0, stream>>>(ctx,  wprojt, b_proj, x,       d_out, nullptr, 1024, 1024, 4);
  ln_kernel<<<16384, 256, 0, stream>>>(out, ln2_g, ln2_b, h);
  gemm256<2><<<16 * 64, 512, 0, stream>>>(h,    wfc1t,  b_fc1,  nullptr, mbuf,  nullptr, 4096, 1024, 16);
  gemm256<1><<< 4 * 64, 512, 0, stream>>>(mbuf, wfc2t,  b_fc2,  out,     d_out, nullptr, 1024, 4096, 4);
}